// Round 2
// baseline (1264.202 us; speedup 1.0000x reference)
//
#include <hip/hip_runtime.h>
#include <hip/hip_bf16.h>

#define N_NODES 100000
#define N_EDGES 1600000
#define IN_DIM 128
#define HID_DIM 128
#define OUT_DIM 40

typedef __attribute__((ext_vector_type(8))) short short8;   // 8 x bf16 (4 VGPRs)
typedef __attribute__((ext_vector_type(4))) float float4v;  // MFMA C/D + float4 loads
typedef __attribute__((ext_vector_type(2))) unsigned int u32x2;
typedef __attribute__((ext_vector_type(2))) float float2v;

typedef unsigned short u16;
typedef unsigned int u32;

__device__ __forceinline__ float bflo(u32 v) { union { u32 u; float f; } c; c.u = v << 16; return c.f; }
__device__ __forceinline__ float bfhi(u32 v) { union { u32 u; float f; } c; c.u = v & 0xffff0000u; return c.f; }
__device__ __forceinline__ u16 f2bf(float f) {  // RNE
    union { float f; u32 u; } c; c.f = f;
    u32 r = c.u + 0x7fffu + ((c.u >> 16) & 1u);
    return (u16)(r >> 16);
}

// ---- f32 -> bf16 conversion (4 elems/thread) -------------------------------

__global__ void k_cvt(const float* __restrict__ s, u16* __restrict__ d, int n4) {
    int i = blockIdx.x * blockDim.x + threadIdx.x;
    if (i < n4) {
        float4v v = reinterpret_cast<const float4v*>(s)[i];
        u32x2 o;
        o.x = ((u32)f2bf(v.y) << 16) | (u32)f2bf(v.x);
        o.y = ((u32)f2bf(v.w) << 16) | (u32)f2bf(v.z);
        reinterpret_cast<u32x2*>(d)[i] = o;
    }
}

// ---- CSR build --------------------------------------------------------------

__global__ void k_count(const int* __restrict__ idx, int* __restrict__ counts) {
    int e = blockIdx.x * blockDim.x + threadIdx.x;
    if (e < N_EDGES) atomicAdd(&counts[idx[N_EDGES + e]], 1);
}

// Segment allocation: wave-level inclusive scan of degrees, one atomic per wave.
__global__ void k_alloc(const int* __restrict__ counts, int* __restrict__ row_start,
                        int* __restrict__ cursor, float* __restrict__ deg_inv,
                        int* __restrict__ gcount) {
    int i = blockIdx.x * blockDim.x + threadIdx.x;
    int lane = threadIdx.x & 63;
    int c = (i < N_NODES) ? counts[i] : 0;
    int incl = c;
    #pragma unroll
    for (int d = 1; d < 64; d <<= 1) {
        int t = __shfl_up(incl, d);
        if (lane >= d) incl += t;
    }
    int wavesum = __shfl(incl, 63);
    int base = 0;
    if (lane == 63) base = atomicAdd(gcount, wavesum);
    base = __shfl(base, 63);
    if (i < N_NODES) {
        int rs = base + incl - c;
        row_start[i] = rs;
        cursor[i] = rs;
        deg_inv[i] = 1.0f / (float)max(c, 1);
    }
}

__global__ void k_fill(const int* __restrict__ idx, int* __restrict__ cursor,
                       int* __restrict__ csr) {
    int e = blockIdx.x * blockDim.x + threadIdx.x;
    if (e < N_EDGES) {
        int s = idx[e];
        int d = idx[N_EDGES + e];
        int p = atomicAdd(&cursor[d], 1);
        csr[p] = s;
    }
}

// ---- Mean aggregation: one wave per dst node, gather-sum (bf16 rows) -------

__global__ void k_agg(const u16* __restrict__ feat,
                      const int* __restrict__ csr,
                      const int* __restrict__ row_start,
                      const int* __restrict__ row_end,
                      const float* __restrict__ deg_inv,
                      u16* __restrict__ agg) {
    int n = blockIdx.x * 4 + (threadIdx.x >> 6);
    int lane = threadIdx.x & 63;
    if (n >= N_NODES) return;
    int s = row_start[n];
    int e = row_end[n];
    const u32* fp = reinterpret_cast<const u32*>(feat);
    float a0 = 0.0f, a1 = 0.0f;
    int src = (s < e) ? csr[s] : 0;
    for (int p = s; p < e; ++p) {
        int nx = (p + 1 < e) ? csr[p + 1] : 0;   // prefetch next src index
        u32 v = fp[src * 64 + lane];
        a0 += bflo(v);
        a1 += bfhi(v);
        src = nx;
    }
    float sc = deg_inv[n];
    u32 out = ((u32)f2bf(a1 * sc) << 16) | (u32)f2bf(a0 * sc);
    reinterpret_cast<u32*>(agg)[n * 64 + lane] = out;
}

// ---- Dense layer 1: h = relu(normalize(agg@W1l^T + b1 + x@W1r^T)) ----------
// MFMA 16x16x32 bf16. One wave = 16 nodes x 128 outs, K=256 (agg half, x half).
// A frag: lane holds A[m=lane&15][k=quad*8+j]; B frag: B[o=lane&15][k=quad*8+j];
// D: col(o)=lane&15, row(node)=quad*4+reg.  (m89/m91-verified layouts)

__global__ __launch_bounds__(256) void k_dense1(
    const u16* __restrict__ agg, const u16* __restrict__ x,
    const u16* __restrict__ W1l, const u16* __restrict__ W1r,
    const float* __restrict__ b1, u16* __restrict__ h) {
    int wave = threadIdx.x >> 6;
    int lane = threadIdx.x & 63;
    int nb = blockIdx.x * 64 + wave * 16;
    int q = lane >> 4;
    int m = lane & 15;
    int arow = nb + m;
    if (arow >= N_NODES) arow = N_NODES - 1;   // clamp loads; stores are guarded

    float4v acc[8];
    #pragma unroll
    for (int ct = 0; ct < 8; ++ct) acc[ct] = (float4v){0.f, 0.f, 0.f, 0.f};

    const u16* Ap[2] = { agg, x };
    const u16* Bp[2] = { W1l, W1r };
    #pragma unroll
    for (int half = 0; half < 2; ++half) {
        const u16* A = Ap[half];
        const u16* B = Bp[half];
        #pragma unroll
        for (int ks = 0; ks < 4; ++ks) {
            int k0 = ks * 32 + q * 8;
            short8 a = *reinterpret_cast<const short8*>(A + arow * 128 + k0);
            #pragma unroll
            for (int ct = 0; ct < 8; ++ct) {
                short8 b = *reinterpret_cast<const short8*>(B + (ct * 16 + m) * 128 + k0);
                acc[ct] = __builtin_amdgcn_mfma_f32_16x16x32_bf16(a, b, acc[ct], 0, 0, 0);
            }
        }
    }

    // epilogue: + bias, L2-normalize node rows, relu, store bf16
    float bias[8];
    #pragma unroll
    for (int ct = 0; ct < 8; ++ct) bias[ct] = b1[ct * 16 + m];

    float nsq[4] = { 0.f, 0.f, 0.f, 0.f };
    #pragma unroll
    for (int ct = 0; ct < 8; ++ct)
        #pragma unroll
        for (int r = 0; r < 4; ++r) {
            float v = acc[ct][r] + bias[ct];
            acc[ct][r] = v;
            nsq[r] += v * v;
        }
    #pragma unroll
    for (int r = 0; r < 4; ++r) {
        float t = nsq[r];
        t += __shfl_xor(t, 1);
        t += __shfl_xor(t, 2);
        t += __shfl_xor(t, 4);
        t += __shfl_xor(t, 8);
        nsq[r] = 1.0f / fmaxf(sqrtf(t), 1e-12f);
    }
    #pragma unroll
    for (int r = 0; r < 4; ++r) {
        int node = nb + q * 4 + r;
        if (node < N_NODES) {
            #pragma unroll
            for (int ct = 0; ct < 8; ++ct) {
                float v = fmaxf(acc[ct][r] * nsq[r], 0.0f);
                h[node * 128 + ct * 16 + m] = f2bf(v);
            }
        }
    }
}

// ---- Dense layer 2 + log_softmax: wave per node, lanes 0..39 = out dims ----
// agg/h are bf16; W2/b2 are f32 (40 KB, L1-resident); output f32.

__global__ __launch_bounds__(256) void k_dense2(
    const u16* __restrict__ agg, const u16* __restrict__ hfeat,
    const float* __restrict__ W2l, const float* __restrict__ W2r,
    const float* __restrict__ b2, float* __restrict__ out) {
    int n = blockIdx.x * 4 + (threadIdx.x >> 6);
    int lane = threadIdx.x & 63;
    if (n >= N_NODES) return;
    bool act = (lane < OUT_DIM);
    int wrow = act ? lane : 0;
    const u32* ap = reinterpret_cast<const u32*>(agg + n * 128);
    const u32* hp = reinterpret_cast<const u32*>(hfeat + n * 128);
    const float2v* wl = reinterpret_cast<const float2v*>(W2l + wrow * 128);
    const float2v* wr = reinterpret_cast<const float2v*>(W2r + wrow * 128);
    float accl = 0.f, accr = 0.f;
    #pragma unroll 8
    for (int k2 = 0; k2 < 64; ++k2) {
        u32 av = ap[k2], hv = hp[k2];
        float2v wlv = wl[k2], wrv = wr[k2];
        accl += bflo(av) * wlv.x + bfhi(av) * wlv.y;
        accr += bflo(hv) * wrv.x + bfhi(hv) * wrv.y;
    }
    float v = act ? (accl + accr + b2[wrow]) : 0.0f;
    // L2 normalize over 40 dims
    float sq = v * v;
    #pragma unroll
    for (int d = 1; d < 64; d <<= 1) sq += __shfl_xor(sq, d);
    v = v / fmaxf(sqrtf(sq), 1e-12f);
    v = fmaxf(v, 0.0f);           // relu
    // log_softmax over 40 dims
    float mv = act ? v : -1e30f;
    #pragma unroll
    for (int d = 1; d < 64; d <<= 1) mv = fmaxf(mv, __shfl_xor(mv, d));
    float ex = act ? __expf(v - mv) : 0.0f;
    float se = ex;
    #pragma unroll
    for (int d = 1; d < 64; d <<= 1) se += __shfl_xor(se, d);
    float res = v - mv - __logf(se);
    if (act) out[n * OUT_DIM + lane] = res;
}

// ---- launch -----------------------------------------------------------------

extern "C" void kernel_launch(void* const* d_in, const int* in_sizes, int n_in,
                              void* d_out, int out_size, void* d_ws, size_t ws_size,
                              hipStream_t stream) {
    const float* x   = (const float*)d_in[0];
    const int*   idx = (const int*)d_in[1];
    const float* W1l = (const float*)d_in[2];
    const float* b1  = (const float*)d_in[3];
    const float* W1r = (const float*)d_in[4];
    const float* W2l = (const float*)d_in[5];
    const float* b2  = (const float*)d_in[6];
    const float* W2r = (const float*)d_in[7];
    float* out = (float*)d_out;

    char* ws = (char*)d_ws;
    int*   counts    = (int*)(ws + 0);          // 400000 B
    int*   gcount    = (int*)(ws + 400000);     // 4 B (memset together w/ counts)
    int*   row_start = (int*)(ws + 400128);     // 400000 B
    int*   cursor    = (int*)(ws + 800256);     // 400000 B (== row_end after fill)
    float* deg_inv   = (float*)(ws + 1200384);  // 400000 B
    int*   csr       = (int*)(ws + 1600512);    // 6400000 B
    u16*   xb        = (u16*)(ws + 8000512);    // 25.6 MB  bf16(x)
    u16*   agg       = (u16*)(ws + 33600512);   // 25.6 MB
    u16*   h         = (u16*)(ws + 59200512);   // 25.6 MB
    u16*   W1lb      = (u16*)(ws + 84800512);   // 32768 B
    u16*   W1rb      = (u16*)(ws + 84833280);   // 32768 B

    // zero degree counters + global cursor (ws is poisoned each call)
    hipMemsetAsync(ws, 0, 400004, stream);

    // bf16 conversions
    k_cvt<<<(N_NODES * IN_DIM / 4 + 255) / 256, 256, 0, stream>>>(x, xb, N_NODES * IN_DIM / 4);
    k_cvt<<<16, 256, 0, stream>>>(W1l, W1lb, HID_DIM * IN_DIM / 4);
    k_cvt<<<16, 256, 0, stream>>>(W1r, W1rb, HID_DIM * IN_DIM / 4);

    // CSR build
    k_count<<<(N_EDGES + 255) / 256, 256, 0, stream>>>(idx, counts);
    k_alloc<<<(N_NODES + 255) / 256, 256, 0, stream>>>(counts, row_start, cursor, deg_inv, gcount);
    k_fill<<<(N_EDGES + 255) / 256, 256, 0, stream>>>(idx, cursor, csr);

    // layer 1
    k_agg<<<N_NODES / 4, 256, 0, stream>>>(xb, csr, row_start, cursor, deg_inv, agg);
    k_dense1<<<(N_NODES + 63) / 64, 256, 0, stream>>>(agg, xb, W1lb, W1rb, b1, h);
    // layer 2
    k_agg<<<N_NODES / 4, 256, 0, stream>>>(h, csr, row_start, cursor, deg_inv, agg);
    k_dense2<<<N_NODES / 4, 256, 0, stream>>>(agg, h, W2l, W2r, b2, out);
}

// Round 3
// 557.977 us; speedup vs baseline: 2.2657x; 2.2657x over previous
//
#include <hip/hip_runtime.h>
#include <hip/hip_bf16.h>

#define N_NODES 100000
#define N_EDGES 1600000
#define IN_DIM 128
#define HID_DIM 128
#define OUT_DIM 40

typedef __attribute__((ext_vector_type(8))) short short8;   // 8 x bf16 (4 VGPRs)
typedef __attribute__((ext_vector_type(4))) float float4v;  // MFMA C/D + float4 loads
typedef __attribute__((ext_vector_type(2))) unsigned int u32x2;

typedef unsigned short u16;
typedef unsigned int u32;

__device__ __forceinline__ float bflo(u32 v) { union { u32 u; float f; } c; c.u = v << 16; return c.f; }
__device__ __forceinline__ float bfhi(u32 v) { union { u32 u; float f; } c; c.u = v & 0xffff0000u; return c.f; }
__device__ __forceinline__ u16 f2bf(float f) {  // RNE
    union { float f; u32 u; } c; c.f = f;
    u32 r = c.u + 0x7fffu + ((c.u >> 16) & 1u);
    return (u16)(r >> 16);
}

// ---- f32 -> bf16 conversion (4 elems/thread) -------------------------------

__global__ void k_cvt(const float* __restrict__ s, u16* __restrict__ d, int n4) {
    int i = blockIdx.x * blockDim.x + threadIdx.x;
    if (i < n4) {
        float4v v = reinterpret_cast<const float4v*>(s)[i];
        u32x2 o;
        o.x = ((u32)f2bf(v.y) << 16) | (u32)f2bf(v.x);
        o.y = ((u32)f2bf(v.w) << 16) | (u32)f2bf(v.z);
        reinterpret_cast<u32x2*>(d)[i] = o;
    }
}

// convert [src_rows][128] f32 -> [dst_rows][128] bf16, rows >= src_rows zeroed
__global__ void k_cvt_pad(const float* __restrict__ s, u16* __restrict__ d,
                          int src_rows, int dst_rows) {
    int i = blockIdx.x * blockDim.x + threadIdx.x;
    int n4 = dst_rows * 128 / 4;
    if (i >= n4) return;
    int row = (i * 4) >> 7;
    u32x2 o;
    if (row < src_rows) {
        float4v v = reinterpret_cast<const float4v*>(s)[i];
        o.x = ((u32)f2bf(v.y) << 16) | (u32)f2bf(v.x);
        o.y = ((u32)f2bf(v.w) << 16) | (u32)f2bf(v.z);
    } else {
        o.x = 0; o.y = 0;
    }
    reinterpret_cast<u32x2*>(d)[i] = o;
}

// ---- CSR build --------------------------------------------------------------

__global__ void k_count(const int* __restrict__ idx, int* __restrict__ counts) {
    int e = blockIdx.x * blockDim.x + threadIdx.x;
    if (e < N_EDGES) atomicAdd(&counts[idx[N_EDGES + e]], 1);
}

__global__ void k_alloc(const int* __restrict__ counts, int* __restrict__ row_start,
                        int* __restrict__ cursor, float* __restrict__ deg_inv,
                        int* __restrict__ gcount) {
    int i = blockIdx.x * blockDim.x + threadIdx.x;
    int lane = threadIdx.x & 63;
    int c = (i < N_NODES) ? counts[i] : 0;
    int incl = c;
    #pragma unroll
    for (int d = 1; d < 64; d <<= 1) {
        int t = __shfl_up(incl, d);
        if (lane >= d) incl += t;
    }
    int wavesum = __shfl(incl, 63);
    int base = 0;
    if (lane == 63) base = atomicAdd(gcount, wavesum);
    base = __shfl(base, 63);
    if (i < N_NODES) {
        int rs = base + incl - c;
        row_start[i] = rs;
        cursor[i] = rs;
        deg_inv[i] = 1.0f / (float)max(c, 1);
    }
}

__global__ void k_fill(const int* __restrict__ idx, int* __restrict__ cursor,
                       int* __restrict__ csr) {
    int e = blockIdx.x * blockDim.x + threadIdx.x;
    if (e < N_EDGES) {
        int s = idx[e];
        int d = idx[N_EDGES + e];
        int p = atomicAdd(&cursor[d], 1);
        csr[p] = s;
    }
}

// ---- Mean aggregation: one wave per dst node, gather-sum (bf16 rows) -------
// Unrolled x4 for memory-level parallelism; loads are independent.

__global__ void k_agg(const u16* __restrict__ feat,
                      const int* __restrict__ csr,
                      const int* __restrict__ row_start,
                      const int* __restrict__ row_end,
                      const float* __restrict__ deg_inv,
                      u16* __restrict__ agg) {
    int n = blockIdx.x * 4 + (threadIdx.x >> 6);
    int lane = threadIdx.x & 63;
    if (n >= N_NODES) return;
    int s = row_start[n];
    int e = row_end[n];
    const u32* fp = reinterpret_cast<const u32*>(feat);
    float a0 = 0.0f, a1 = 0.0f;
    int p = s;
    for (; p + 4 <= e; p += 4) {
        int s0 = csr[p], s1 = csr[p + 1], s2 = csr[p + 2], s3 = csr[p + 3];
        u32 v0 = fp[s0 * 64 + lane];
        u32 v1 = fp[s1 * 64 + lane];
        u32 v2 = fp[s2 * 64 + lane];
        u32 v3 = fp[s3 * 64 + lane];
        a0 += bflo(v0) + bflo(v1) + bflo(v2) + bflo(v3);
        a1 += bfhi(v0) + bfhi(v1) + bfhi(v2) + bfhi(v3);
    }
    for (; p < e; ++p) {
        u32 v = fp[csr[p] * 64 + lane];
        a0 += bflo(v);
        a1 += bfhi(v);
    }
    float sc = deg_inv[n];
    u32 out = ((u32)f2bf(a1 * sc) << 16) | (u32)f2bf(a0 * sc);
    reinterpret_cast<u32*>(agg)[n * 64 + lane] = out;
}

// ---- Dense layer 1: h = relu(normalize(agg@W1l^T + b1 + x@W1r^T)) ----------
// MFMA 16x16x32 bf16. One wave = 16 nodes x 128 outs, K=256 (agg half, x half).
// D: col(o)=lane&15, row(node)=quad*4+reg.

__global__ __launch_bounds__(256) void k_dense1(
    const u16* __restrict__ agg, const u16* __restrict__ x,
    const u16* __restrict__ W1l, const u16* __restrict__ W1r,
    const float* __restrict__ b1, u16* __restrict__ h) {
    int wave = threadIdx.x >> 6;
    int lane = threadIdx.x & 63;
    int nb = blockIdx.x * 64 + wave * 16;
    int q = lane >> 4;
    int m = lane & 15;
    int arow = nb + m;
    if (arow >= N_NODES) arow = N_NODES - 1;   // clamp loads; stores are guarded

    float4v acc[8];
    #pragma unroll
    for (int ct = 0; ct < 8; ++ct) acc[ct] = (float4v){0.f, 0.f, 0.f, 0.f};

    const u16* Ap[2] = { agg, x };
    const u16* Bp[2] = { W1l, W1r };
    #pragma unroll
    for (int half = 0; half < 2; ++half) {
        const u16* A = Ap[half];
        const u16* B = Bp[half];
        #pragma unroll
        for (int ks = 0; ks < 4; ++ks) {
            int k0 = ks * 32 + q * 8;
            short8 a = *reinterpret_cast<const short8*>(A + arow * 128 + k0);
            #pragma unroll
            for (int ct = 0; ct < 8; ++ct) {
                short8 b = *reinterpret_cast<const short8*>(B + (ct * 16 + m) * 128 + k0);
                acc[ct] = __builtin_amdgcn_mfma_f32_16x16x32_bf16(a, b, acc[ct], 0, 0, 0);
            }
        }
    }

    float bias[8];
    #pragma unroll
    for (int ct = 0; ct < 8; ++ct) bias[ct] = b1[ct * 16 + m];

    float nsq[4] = { 0.f, 0.f, 0.f, 0.f };
    #pragma unroll
    for (int ct = 0; ct < 8; ++ct)
        #pragma unroll
        for (int r = 0; r < 4; ++r) {
            float v = acc[ct][r] + bias[ct];
            acc[ct][r] = v;
            nsq[r] += v * v;
        }
    #pragma unroll
    for (int r = 0; r < 4; ++r) {
        float t = nsq[r];
        t += __shfl_xor(t, 1);
        t += __shfl_xor(t, 2);
        t += __shfl_xor(t, 4);
        t += __shfl_xor(t, 8);
        nsq[r] = 1.0f / fmaxf(sqrtf(t), 1e-12f);
    }
    #pragma unroll
    for (int r = 0; r < 4; ++r) {
        int node = nb + q * 4 + r;
        if (node < N_NODES) {
            #pragma unroll
            for (int ct = 0; ct < 8; ++ct) {
                float v = fmaxf(acc[ct][r] * nsq[r], 0.0f);
                h[node * 128 + ct * 16 + m] = f2bf(v);
            }
        }
    }
}

// ---- Dense layer 2 + log_softmax, MFMA version ------------------------------
// One wave = 16 nodes x 48 cols (3 ct tiles; cols 40..47 are zero-padded in
// W2lb/W2rb so they contribute 0). Fused: bias, L2-normalize, relu,
// log_softmax (masked), f32 store.

__global__ __launch_bounds__(256) void k_dense2(
    const u16* __restrict__ agg, const u16* __restrict__ hfeat,
    const u16* __restrict__ W2lb, const u16* __restrict__ W2rb,
    const float* __restrict__ b2, float* __restrict__ out) {
    int wave = threadIdx.x >> 6;
    int lane = threadIdx.x & 63;
    int nb = blockIdx.x * 64 + wave * 16;
    int q = lane >> 4;
    int m = lane & 15;
    int arow = nb + m;
    if (arow >= N_NODES) arow = N_NODES - 1;

    float4v acc[3];
    #pragma unroll
    for (int ct = 0; ct < 3; ++ct) acc[ct] = (float4v){0.f, 0.f, 0.f, 0.f};

    const u16* Ap[2] = { agg, hfeat };
    const u16* Bp[2] = { W2lb, W2rb };
    #pragma unroll
    for (int half = 0; half < 2; ++half) {
        const u16* A = Ap[half];
        const u16* B = Bp[half];
        #pragma unroll
        for (int ks = 0; ks < 4; ++ks) {
            int k0 = ks * 32 + q * 8;
            short8 a = *reinterpret_cast<const short8*>(A + arow * 128 + k0);
            #pragma unroll
            for (int ct = 0; ct < 3; ++ct) {
                short8 b = *reinterpret_cast<const short8*>(B + (ct * 16 + m) * 128 + k0);
                acc[ct] = __builtin_amdgcn_mfma_f32_16x16x32_bf16(a, b, acc[ct], 0, 0, 0);
            }
        }
    }

    float bias[3];
    #pragma unroll
    for (int ct = 0; ct < 3; ++ct) {
        int row = ct * 16 + m;
        bias[ct] = (row < OUT_DIM) ? b2[row] : 0.0f;
    }

    // bias + norm^2 (padded cols contribute exactly 0: zero weights, zero bias)
    float nsq[4] = { 0.f, 0.f, 0.f, 0.f };
    #pragma unroll
    for (int ct = 0; ct < 3; ++ct)
        #pragma unroll
        for (int r = 0; r < 4; ++r) {
            float v = acc[ct][r] + bias[ct];
            acc[ct][r] = v;
            nsq[r] += v * v;
        }
    #pragma unroll
    for (int r = 0; r < 4; ++r) {
        float t = nsq[r];
        t += __shfl_xor(t, 1);
        t += __shfl_xor(t, 2);
        t += __shfl_xor(t, 4);
        t += __shfl_xor(t, 8);
        nsq[r] = 1.0f / fmaxf(sqrtf(t), 1e-12f);
    }

    // normalize + relu; running max (relu vals >= 0, padded zeros harmless)
    float mv[4] = { 0.f, 0.f, 0.f, 0.f };
    #pragma unroll
    for (int ct = 0; ct < 3; ++ct)
        #pragma unroll
        for (int r = 0; r < 4; ++r) {
            float v = fmaxf(acc[ct][r] * nsq[r], 0.0f);
            acc[ct][r] = v;
            mv[r] = fmaxf(mv[r], v);
        }
    #pragma unroll
    for (int r = 0; r < 4; ++r) {
        float t = mv[r];
        t = fmaxf(t, __shfl_xor(t, 1));
        t = fmaxf(t, __shfl_xor(t, 2));
        t = fmaxf(t, __shfl_xor(t, 4));
        t = fmaxf(t, __shfl_xor(t, 8));
        mv[r] = t;
    }

    // exp-sum over the 40 real cols only
    float se[4] = { 0.f, 0.f, 0.f, 0.f };
    #pragma unroll
    for (int ct = 0; ct < 3; ++ct) {
        bool valid = (ct < 2) || (m < 8);
        #pragma unroll
        for (int r = 0; r < 4; ++r)
            se[r] += valid ? __expf(acc[ct][r] - mv[r]) : 0.0f;
    }
    #pragma unroll
    for (int r = 0; r < 4; ++r) {
        float t = se[r];
        t += __shfl_xor(t, 1);
        t += __shfl_xor(t, 2);
        t += __shfl_xor(t, 4);
        t += __shfl_xor(t, 8);
        se[r] = __logf(t);
    }

    #pragma unroll
    for (int r = 0; r < 4; ++r) {
        int node = nb + q * 4 + r;
        if (node < N_NODES) {
            #pragma unroll
            for (int ct = 0; ct < 3; ++ct) {
                int col = ct * 16 + m;
                if (col < OUT_DIM)
                    out[node * OUT_DIM + col] = acc[ct][r] - mv[r] - se[r];
            }
        }
    }
}

// ---- launch -----------------------------------------------------------------

extern "C" void kernel_launch(void* const* d_in, const int* in_sizes, int n_in,
                              void* d_out, int out_size, void* d_ws, size_t ws_size,
                              hipStream_t stream) {
    const float* x   = (const float*)d_in[0];
    const int*   idx = (const int*)d_in[1];
    const float* W1l = (const float*)d_in[2];
    const float* b1  = (const float*)d_in[3];
    const float* W1r = (const float*)d_in[4];
    const float* W2l = (const float*)d_in[5];
    const float* b2  = (const float*)d_in[6];
    const float* W2r = (const float*)d_in[7];
    float* out = (float*)d_out;

    char* ws = (char*)d_ws;
    int*   counts    = (int*)(ws + 0);          // 400000 B
    int*   gcount    = (int*)(ws + 400000);     // 4 B (memset together w/ counts)
    int*   row_start = (int*)(ws + 400128);     // 400000 B
    int*   cursor    = (int*)(ws + 800256);     // 400000 B (== row_end after fill)
    float* deg_inv   = (float*)(ws + 1200384);  // 400000 B
    int*   csr       = (int*)(ws + 1600512);    // 6400000 B
    u16*   xb        = (u16*)(ws + 8000512);    // 25.6 MB  bf16(x)
    u16*   agg       = (u16*)(ws + 33600512);   // 25.6 MB
    u16*   h         = (u16*)(ws + 59200512);   // 25.6 MB
    u16*   W1lb      = (u16*)(ws + 84800512);   // 32768 B
    u16*   W1rb      = (u16*)(ws + 84833280);   // 32768 B
    u16*   W2lb      = (u16*)(ws + 84866048);   // 12288 B (48x128 padded)
    u16*   W2rb      = (u16*)(ws + 84878336);   // 12288 B

    hipMemsetAsync(ws, 0, 400004, stream);

    // bf16 conversions
    k_cvt<<<(N_NODES * IN_DIM / 4 + 255) / 256, 256, 0, stream>>>(x, xb, N_NODES * IN_DIM / 4);
    k_cvt<<<16, 256, 0, stream>>>(W1l, W1lb, HID_DIM * IN_DIM / 4);
    k_cvt<<<16, 256, 0, stream>>>(W1r, W1rb, HID_DIM * IN_DIM / 4);
    k_cvt_pad<<<6, 256, 0, stream>>>(W2l, W2lb, OUT_DIM, 48);
    k_cvt_pad<<<6, 256, 0, stream>>>(W2r, W2rb, OUT_DIM, 48);

    // CSR build
    k_count<<<(N_EDGES + 255) / 256, 256, 0, stream>>>(idx, counts);
    k_alloc<<<(N_NODES + 255) / 256, 256, 0, stream>>>(counts, row_start, cursor, deg_inv, gcount);
    k_fill<<<(N_EDGES + 255) / 256, 256, 0, stream>>>(idx, cursor, csr);

    // layer 1
    k_agg<<<N_NODES / 4, 256, 0, stream>>>(xb, csr, row_start, cursor, deg_inv, agg);
    k_dense1<<<(N_NODES + 63) / 64, 256, 0, stream>>>(agg, xb, W1lb, W1rb, b1, h);
    // layer 2
    k_agg<<<N_NODES / 4, 256, 0, stream>>>(h, csr, row_start, cursor, deg_inv, agg);
    k_dense2<<<(N_NODES + 63) / 64, 256, 0, stream>>>(agg, h, W2lb, W2rb, b2, out);
}

// Round 4
// 412.742 us; speedup vs baseline: 3.0629x; 1.3519x over previous
//
#include <hip/hip_runtime.h>
#include <hip/hip_bf16.h>

#define N_NODES 100000
#define N_EDGES 1600000
#define IN_DIM 128
#define HID_DIM 128
#define OUT_DIM 40

#define BSHIFT 9                 // 512 nodes per bucket
#define NBUCK 196                // ceil(100000/512)
#define CHUNK 4096               // edges per k_bscatter block
#define NCHUNK ((N_EDGES + CHUNK - 1) / CHUNK)

typedef __attribute__((ext_vector_type(8))) short short8;   // 8 x bf16 (4 VGPRs)
typedef __attribute__((ext_vector_type(4))) float float4v;  // MFMA C/D + float4 loads
typedef __attribute__((ext_vector_type(2))) unsigned int u32x2;

typedef unsigned short u16;
typedef unsigned int u32;
typedef unsigned long long u64;

__device__ __forceinline__ float bflo(u32 v) { union { u32 u; float f; } c; c.u = v << 16; return c.f; }
__device__ __forceinline__ float bfhi(u32 v) { union { u32 u; float f; } c; c.u = v & 0xffff0000u; return c.f; }
__device__ __forceinline__ u16 f2bf(float f) {  // RNE
    union { float f; u32 u; } c; c.f = f;
    u32 r = c.u + 0x7fffu + ((c.u >> 16) & 1u);
    return (u16)(r >> 16);
}

// ---- f32 -> bf16 conversion (4 elems/thread) -------------------------------

__global__ void k_cvt(const float* __restrict__ s, u16* __restrict__ d, int n4) {
    int i = blockIdx.x * blockDim.x + threadIdx.x;
    if (i < n4) {
        float4v v = reinterpret_cast<const float4v*>(s)[i];
        u32x2 o;
        o.x = ((u32)f2bf(v.y) << 16) | (u32)f2bf(v.x);
        o.y = ((u32)f2bf(v.w) << 16) | (u32)f2bf(v.z);
        reinterpret_cast<u32x2*>(d)[i] = o;
    }
}

// convert [src_rows][128] f32 -> [dst_rows][128] bf16, rows >= src_rows zeroed
__global__ void k_cvt_pad(const float* __restrict__ s, u16* __restrict__ d,
                          int src_rows, int dst_rows) {
    int i = blockIdx.x * blockDim.x + threadIdx.x;
    int n4 = dst_rows * 128 / 4;
    if (i >= n4) return;
    int row = (i * 4) >> 7;
    u32x2 o;
    if (row < src_rows) {
        float4v v = reinterpret_cast<const float4v*>(s)[i];
        o.x = ((u32)f2bf(v.y) << 16) | (u32)f2bf(v.x);
        o.y = ((u32)f2bf(v.w) << 16) | (u32)f2bf(v.z);
    } else {
        o.x = 0; o.y = 0;
    }
    reinterpret_cast<u32x2*>(d)[i] = o;
}

// ---- CSR build: radix partition by dst bucket -------------------------------

// 1. bucket sizes via LDS histogram (196 buckets of 512 nodes)
__global__ __launch_bounds__(256) void k_bcount(const int* __restrict__ idx,
                                                int* __restrict__ bucket_size) {
    __shared__ int cnt[NBUCK];
    int t = threadIdx.x;
    for (int i = t; i < NBUCK; i += 256) cnt[i] = 0;
    __syncthreads();
    int base = blockIdx.x * CHUNK;
    int n = min(CHUNK, N_EDGES - base);
    for (int i = t; i < n; i += 256)
        atomicAdd(&cnt[idx[N_EDGES + base + i] >> BSHIFT], 1);
    __syncthreads();
    for (int i = t; i < NBUCK; i += 256)
        if (cnt[i]) atomicAdd(&bucket_size[i], cnt[i]);
}

// 2. exclusive scan of bucket sizes -> bucket_base (== csr segment base), cursor
__global__ __launch_bounds__(256) void k_bscan(const int* __restrict__ bucket_size,
                                               int* __restrict__ bucket_base,
                                               int* __restrict__ bucket_cur) {
    __shared__ int sa[256], sb[256];
    int t = threadIdx.x;
    int v = (t < NBUCK) ? bucket_size[t] : 0;
    sa[t] = v;
    __syncthreads();
    int *s = sa, *d = sb;
    for (int dd = 1; dd < 256; dd <<= 1) {
        d[t] = s[t] + ((t >= dd) ? s[t - dd] : 0);
        __syncthreads();
        int* tm = s; s = d; d = tm;
    }
    if (t < NBUCK) {
        int base = s[t] - v;   // exclusive prefix
        bucket_base[t] = base;
        bucket_cur[t] = base;
    }
}

// 3. LDS-staged partition: group each block's 4096 edges by bucket, flush
//    packed (dst<<32|src) records to contiguous per-bucket global segments.
__global__ __launch_bounds__(256) void k_bscatter(const int* __restrict__ idx,
                                                  int* __restrict__ bucket_cur,
                                                  u64* __restrict__ rec) {
    __shared__ int cnt[NBUCK], lofs[NBUCK], gbase[NBUCK], cnt2[NBUCK];
    __shared__ int sa[256], sb[256];
    __shared__ u64 lrec[CHUNK];
    int t = threadIdx.x;
    for (int i = t; i < NBUCK; i += 256) { cnt[i] = 0; cnt2[i] = 0; }
    __syncthreads();
    int base = blockIdx.x * CHUNK;
    int n = min(CHUNK, N_EDGES - base);
    for (int i = t; i < n; i += 256)
        atomicAdd(&cnt[idx[N_EDGES + base + i] >> BSHIFT], 1);
    __syncthreads();
    // exclusive scan of cnt -> lofs; reserve global space
    int v = (t < NBUCK) ? cnt[t] : 0;
    sa[t] = v;
    __syncthreads();
    int *s = sa, *d = sb;
    for (int dd = 1; dd < 256; dd <<= 1) {
        d[t] = s[t] + ((t >= dd) ? s[t - dd] : 0);
        __syncthreads();
        int* tm = s; s = d; d = tm;
    }
    if (t < NBUCK) {
        lofs[t] = s[t] - v;
        gbase[t] = v ? atomicAdd(&bucket_cur[t], v) : 0;
    }
    __syncthreads();
    // place edges into LDS grouped by bucket
    for (int i = t; i < n; i += 256) {
        int srcv = idx[base + i];
        int dstv = idx[N_EDGES + base + i];
        int b = dstv >> BSHIFT;
        int p = lofs[b] + atomicAdd(&cnt2[b], 1);
        lrec[p] = ((u64)(u32)dstv << 32) | (u32)srcv;
    }
    __syncthreads();
    // flush: slot order == per-bucket contiguous global order
    for (int i = t; i < n; i += 256) {
        u64 r = lrec[i];
        int b = ((int)(r >> 32)) >> BSHIFT;
        rec[gbase[b] + (i - lofs[b])] = r;
    }
}

// 4. one block per bucket: LDS degree histogram + scan -> row_start/row_end/
//    deg_inv, then scatter src into the bucket's contiguous csr segment.
__global__ __launch_bounds__(256) void k_bfill(const u64* __restrict__ rec,
                                               const int* __restrict__ bucket_base,
                                               const int* __restrict__ bucket_size,
                                               int* __restrict__ row_start,
                                               int* __restrict__ row_end,
                                               float* __restrict__ deg_inv,
                                               int* __restrict__ csr) {
    __shared__ int deg[512], cur[512];
    __shared__ int sa[512], sb[512];
    int t = threadIdx.x;
    int b = blockIdx.x;
    int node0 = b << BSHIFT;
    int nn = min(512, N_NODES - node0);
    int ebase = bucket_base[b];
    int esz = bucket_size[b];
    for (int i = t; i < 512; i += 256) deg[i] = 0;
    __syncthreads();
    for (int i = t; i < esz; i += 256)
        atomicAdd(&deg[((int)(rec[ebase + i] >> 32)) & 511], 1);
    __syncthreads();
    for (int i = t; i < 512; i += 256) sa[i] = deg[i];
    __syncthreads();
    int *s = sa, *d = sb;
    for (int dd = 1; dd < 512; dd <<= 1) {
        for (int i = t; i < 512; i += 256) d[i] = s[i] + ((i >= dd) ? s[i - dd] : 0);
        __syncthreads();
        int* tm = s; s = d; d = tm;
    }
    for (int i = t; i < 512; i += 256) {
        int excl = s[i] - deg[i];
        cur[i] = excl;
        if (i < nn) {
            row_start[node0 + i] = ebase + excl;
            row_end[node0 + i]   = ebase + s[i];
            deg_inv[node0 + i]   = 1.0f / (float)max(deg[i], 1);
        }
    }
    __syncthreads();
    for (int i = t; i < esz; i += 256) {
        u64 r = rec[ebase + i];
        int dl = ((int)(r >> 32)) & 511;
        int p = atomicAdd(&cur[dl], 1);
        csr[ebase + p] = (int)(r & 0xffffffffu);
    }
}

// ---- Mean aggregation: one wave per dst node, gather-sum (bf16 rows) -------

__global__ void k_agg(const u16* __restrict__ feat,
                      const int* __restrict__ csr,
                      const int* __restrict__ row_start,
                      const int* __restrict__ row_end,
                      const float* __restrict__ deg_inv,
                      u16* __restrict__ agg) {
    int n = blockIdx.x * 4 + (threadIdx.x >> 6);
    int lane = threadIdx.x & 63;
    if (n >= N_NODES) return;
    int s = row_start[n];
    int e = row_end[n];
    const u32* fp = reinterpret_cast<const u32*>(feat);
    float a0 = 0.0f, a1 = 0.0f;
    int p = s;
    for (; p + 4 <= e; p += 4) {
        int s0 = csr[p], s1 = csr[p + 1], s2 = csr[p + 2], s3 = csr[p + 3];
        u32 v0 = fp[s0 * 64 + lane];
        u32 v1 = fp[s1 * 64 + lane];
        u32 v2 = fp[s2 * 64 + lane];
        u32 v3 = fp[s3 * 64 + lane];
        a0 += bflo(v0) + bflo(v1) + bflo(v2) + bflo(v3);
        a1 += bfhi(v0) + bfhi(v1) + bfhi(v2) + bfhi(v3);
    }
    for (; p < e; ++p) {
        u32 v = fp[csr[p] * 64 + lane];
        a0 += bflo(v);
        a1 += bfhi(v);
    }
    float sc = deg_inv[n];
    u32 out = ((u32)f2bf(a1 * sc) << 16) | (u32)f2bf(a0 * sc);
    reinterpret_cast<u32*>(agg)[n * 64 + lane] = out;
}

// ---- Dense layer 1: h = relu(normalize(agg@W1l^T + b1 + x@W1r^T)) ----------
// MFMA 16x16x32 bf16. One wave = 16 nodes x 128 outs, K=256 (agg half, x half).
// D: col(o)=lane&15, row(node)=quad*4+reg.

__global__ __launch_bounds__(256) void k_dense1(
    const u16* __restrict__ agg, const u16* __restrict__ x,
    const u16* __restrict__ W1l, const u16* __restrict__ W1r,
    const float* __restrict__ b1, u16* __restrict__ h) {
    int wave = threadIdx.x >> 6;
    int lane = threadIdx.x & 63;
    int nb = blockIdx.x * 64 + wave * 16;
    int q = lane >> 4;
    int m = lane & 15;
    int arow = nb + m;
    if (arow >= N_NODES) arow = N_NODES - 1;   // clamp loads; stores are guarded

    float4v acc[8];
    #pragma unroll
    for (int ct = 0; ct < 8; ++ct) acc[ct] = (float4v){0.f, 0.f, 0.f, 0.f};

    const u16* Ap[2] = { agg, x };
    const u16* Bp[2] = { W1l, W1r };
    #pragma unroll
    for (int half = 0; half < 2; ++half) {
        const u16* A = Ap[half];
        const u16* B = Bp[half];
        #pragma unroll
        for (int ks = 0; ks < 4; ++ks) {
            int k0 = ks * 32 + q * 8;
            short8 a = *reinterpret_cast<const short8*>(A + arow * 128 + k0);
            #pragma unroll
            for (int ct = 0; ct < 8; ++ct) {
                short8 b = *reinterpret_cast<const short8*>(B + (ct * 16 + m) * 128 + k0);
                acc[ct] = __builtin_amdgcn_mfma_f32_16x16x32_bf16(a, b, acc[ct], 0, 0, 0);
            }
        }
    }

    float bias[8];
    #pragma unroll
    for (int ct = 0; ct < 8; ++ct) bias[ct] = b1[ct * 16 + m];

    float nsq[4] = { 0.f, 0.f, 0.f, 0.f };
    #pragma unroll
    for (int ct = 0; ct < 8; ++ct)
        #pragma unroll
        for (int r = 0; r < 4; ++r) {
            float v = acc[ct][r] + bias[ct];
            acc[ct][r] = v;
            nsq[r] += v * v;
        }
    #pragma unroll
    for (int r = 0; r < 4; ++r) {
        float t = nsq[r];
        t += __shfl_xor(t, 1);
        t += __shfl_xor(t, 2);
        t += __shfl_xor(t, 4);
        t += __shfl_xor(t, 8);
        nsq[r] = 1.0f / fmaxf(sqrtf(t), 1e-12f);
    }
    #pragma unroll
    for (int r = 0; r < 4; ++r) {
        int node = nb + q * 4 + r;
        if (node < N_NODES) {
            #pragma unroll
            for (int ct = 0; ct < 8; ++ct) {
                float v = fmaxf(acc[ct][r] * nsq[r], 0.0f);
                h[node * 128 + ct * 16 + m] = f2bf(v);
            }
        }
    }
}

// ---- Dense layer 2 + log_softmax, MFMA version ------------------------------
// One wave = 16 nodes x 48 cols (3 ct tiles; cols 40..47 zero-padded weights).

__global__ __launch_bounds__(256) void k_dense2(
    const u16* __restrict__ agg, const u16* __restrict__ hfeat,
    const u16* __restrict__ W2lb, const u16* __restrict__ W2rb,
    const float* __restrict__ b2, float* __restrict__ out) {
    int wave = threadIdx.x >> 6;
    int lane = threadIdx.x & 63;
    int nb = blockIdx.x * 64 + wave * 16;
    int q = lane >> 4;
    int m = lane & 15;
    int arow = nb + m;
    if (arow >= N_NODES) arow = N_NODES - 1;

    float4v acc[3];
    #pragma unroll
    for (int ct = 0; ct < 3; ++ct) acc[ct] = (float4v){0.f, 0.f, 0.f, 0.f};

    const u16* Ap[2] = { agg, hfeat };
    const u16* Bp[2] = { W2lb, W2rb };
    #pragma unroll
    for (int half = 0; half < 2; ++half) {
        const u16* A = Ap[half];
        const u16* B = Bp[half];
        #pragma unroll
        for (int ks = 0; ks < 4; ++ks) {
            int k0 = ks * 32 + q * 8;
            short8 a = *reinterpret_cast<const short8*>(A + arow * 128 + k0);
            #pragma unroll
            for (int ct = 0; ct < 3; ++ct) {
                short8 b = *reinterpret_cast<const short8*>(B + (ct * 16 + m) * 128 + k0);
                acc[ct] = __builtin_amdgcn_mfma_f32_16x16x32_bf16(a, b, acc[ct], 0, 0, 0);
            }
        }
    }

    float bias[3];
    #pragma unroll
    for (int ct = 0; ct < 3; ++ct) {
        int row = ct * 16 + m;
        bias[ct] = (row < OUT_DIM) ? b2[row] : 0.0f;
    }

    float nsq[4] = { 0.f, 0.f, 0.f, 0.f };
    #pragma unroll
    for (int ct = 0; ct < 3; ++ct)
        #pragma unroll
        for (int r = 0; r < 4; ++r) {
            float v = acc[ct][r] + bias[ct];
            acc[ct][r] = v;
            nsq[r] += v * v;
        }
    #pragma unroll
    for (int r = 0; r < 4; ++r) {
        float t = nsq[r];
        t += __shfl_xor(t, 1);
        t += __shfl_xor(t, 2);
        t += __shfl_xor(t, 4);
        t += __shfl_xor(t, 8);
        nsq[r] = 1.0f / fmaxf(sqrtf(t), 1e-12f);
    }

    float mv[4] = { 0.f, 0.f, 0.f, 0.f };
    #pragma unroll
    for (int ct = 0; ct < 3; ++ct)
        #pragma unroll
        for (int r = 0; r < 4; ++r) {
            float v = fmaxf(acc[ct][r] * nsq[r], 0.0f);
            acc[ct][r] = v;
            mv[r] = fmaxf(mv[r], v);
        }
    #pragma unroll
    for (int r = 0; r < 4; ++r) {
        float t = mv[r];
        t = fmaxf(t, __shfl_xor(t, 1));
        t = fmaxf(t, __shfl_xor(t, 2));
        t = fmaxf(t, __shfl_xor(t, 4));
        t = fmaxf(t, __shfl_xor(t, 8));
        mv[r] = t;
    }

    float se[4] = { 0.f, 0.f, 0.f, 0.f };
    #pragma unroll
    for (int ct = 0; ct < 3; ++ct) {
        bool valid = (ct < 2) || (m < 8);
        #pragma unroll
        for (int r = 0; r < 4; ++r)
            se[r] += valid ? __expf(acc[ct][r] - mv[r]) : 0.0f;
    }
    #pragma unroll
    for (int r = 0; r < 4; ++r) {
        float t = se[r];
        t += __shfl_xor(t, 1);
        t += __shfl_xor(t, 2);
        t += __shfl_xor(t, 4);
        t += __shfl_xor(t, 8);
        se[r] = __logf(t);
    }

    #pragma unroll
    for (int r = 0; r < 4; ++r) {
        int node = nb + q * 4 + r;
        if (node < N_NODES) {
            #pragma unroll
            for (int ct = 0; ct < 3; ++ct) {
                int col = ct * 16 + m;
                if (col < OUT_DIM)
                    out[node * OUT_DIM + col] = acc[ct][r] - mv[r] - se[r];
            }
        }
    }
}

// ---- launch -----------------------------------------------------------------

extern "C" void kernel_launch(void* const* d_in, const int* in_sizes, int n_in,
                              void* d_out, int out_size, void* d_ws, size_t ws_size,
                              hipStream_t stream) {
    const float* x   = (const float*)d_in[0];
    const int*   idx = (const int*)d_in[1];
    const float* W1l = (const float*)d_in[2];
    const float* b1  = (const float*)d_in[3];
    const float* W1r = (const float*)d_in[4];
    const float* W2l = (const float*)d_in[5];
    const float* b2  = (const float*)d_in[6];
    const float* W2r = (const float*)d_in[7];
    float* out = (float*)d_out;

    char* ws = (char*)d_ws;
    int*   bucket_size = (int*)(ws + 0);        // 784 B (memset 0)
    int*   bucket_base = (int*)(ws + 4096);     // 784 B
    int*   bucket_cur  = (int*)(ws + 8192);     // 784 B
    int*   row_start   = (int*)(ws + 16384);    // 400000 B
    int*   row_end     = (int*)(ws + 416384);   // 400000 B
    float* deg_inv     = (float*)(ws + 816384); // 400000 B
    int*   csr         = (int*)(ws + 1216384);  // 6.4 MB -> ends 7616384
    u16*   xb          = (u16*)(ws + 7616512);  // 25.6 MB bf16(x)
    u16*   agg         = (u16*)(ws + 33216512); // 25.6 MB
    u16*   h           = (u16*)(ws + 58816512); // 25.6 MB
    u64*   rec         = (u64*)(ws + 58816512); // 12.8 MB, ALIASES h (disjoint lifetime)
    u16*   W1lb        = (u16*)(ws + 84416512); // 32768 B
    u16*   W1rb        = (u16*)(ws + 84449280); // 32768 B
    u16*   W2lb        = (u16*)(ws + 84482048); // 12288 B (48x128 padded)
    u16*   W2rb        = (u16*)(ws + 84494336); // 12288 B

    hipMemsetAsync(bucket_size, 0, NBUCK * sizeof(int), stream);

    // bf16 conversions
    k_cvt<<<(N_NODES * IN_DIM / 4 + 255) / 256, 256, 0, stream>>>(x, xb, N_NODES * IN_DIM / 4);
    k_cvt<<<16, 256, 0, stream>>>(W1l, W1lb, HID_DIM * IN_DIM / 4);
    k_cvt<<<16, 256, 0, stream>>>(W1r, W1rb, HID_DIM * IN_DIM / 4);
    k_cvt_pad<<<6, 256, 0, stream>>>(W2l, W2lb, OUT_DIM, 48);
    k_cvt_pad<<<6, 256, 0, stream>>>(W2r, W2rb, OUT_DIM, 48);

    // CSR build via radix partition
    k_bcount<<<NCHUNK, 256, 0, stream>>>(idx, bucket_size);
    k_bscan<<<1, 256, 0, stream>>>(bucket_size, bucket_base, bucket_cur);
    k_bscatter<<<NCHUNK, 256, 0, stream>>>(idx, bucket_cur, rec);
    k_bfill<<<NBUCK, 256, 0, stream>>>(rec, bucket_base, bucket_size,
                                       row_start, row_end, deg_inv, csr);

    // layer 1
    k_agg<<<N_NODES / 4, 256, 0, stream>>>(xb, csr, row_start, row_end, deg_inv, agg);
    k_dense1<<<(N_NODES + 63) / 64, 256, 0, stream>>>(agg, xb, W1lb, W1rb, b1, h);
    // layer 2
    k_agg<<<N_NODES / 4, 256, 0, stream>>>(h, csr, row_start, row_end, deg_inv, agg);
    k_dense2<<<(N_NODES + 63) / 64, 256, 0, stream>>>(agg, h, W2lb, W2rb, b2, out);
}

// Round 5
// 388.294 us; speedup vs baseline: 3.2558x; 1.0630x over previous
//
#include <hip/hip_runtime.h>
#include <hip/hip_bf16.h>

#define N_NODES 100000
#define N_EDGES 1600000
#define IN_DIM 128
#define HID_DIM 128
#define OUT_DIM 40

#define BSHIFT 9                 // 512 nodes per bucket
#define NBUCK 196                // ceil(100000/512)
#define CHUNK 4096               // edges per k_bscatter block
#define NCHUNK ((N_EDGES + CHUNK - 1) / CHUNK)

typedef __attribute__((ext_vector_type(8))) short short8;   // 8 x bf16 (4 VGPRs)
typedef __attribute__((ext_vector_type(4))) float float4v;  // MFMA C/D + float4 loads
typedef __attribute__((ext_vector_type(2))) unsigned int u32x2;

typedef unsigned short u16;
typedef unsigned int u32;
typedef unsigned long long u64;

__device__ __forceinline__ float bflo(u32 v) { union { u32 u; float f; } c; c.u = v << 16; return c.f; }
__device__ __forceinline__ float bfhi(u32 v) { union { u32 u; float f; } c; c.u = v & 0xffff0000u; return c.f; }
__device__ __forceinline__ u16 f2bf(float f) {  // RNE
    union { float f; u32 u; } c; c.f = f;
    u32 r = c.u + 0x7fffu + ((c.u >> 16) & 1u);
    return (u16)(r >> 16);
}

// ---- f32 -> bf16 conversion (4 elems/thread) -------------------------------

__global__ void k_cvt(const float* __restrict__ s, u16* __restrict__ d, int n4) {
    int i = blockIdx.x * blockDim.x + threadIdx.x;
    if (i < n4) {
        float4v v = reinterpret_cast<const float4v*>(s)[i];
        u32x2 o;
        o.x = ((u32)f2bf(v.y) << 16) | (u32)f2bf(v.x);
        o.y = ((u32)f2bf(v.w) << 16) | (u32)f2bf(v.z);
        reinterpret_cast<u32x2*>(d)[i] = o;
    }
}

// all 4 weight matrices in one launch; W2 targets zero-padded to 48 rows
__global__ __launch_bounds__(256) void k_cvtw(
    const float* __restrict__ w1l, const float* __restrict__ w1r,
    const float* __restrict__ w2l, const float* __restrict__ w2r,
    u16* __restrict__ w1lb, u16* __restrict__ w1rb,
    u16* __restrict__ w2lb, u16* __restrict__ w2rb) {
    int i = blockIdx.x * 256 + threadIdx.x;   // granule = 4 elems
    const int G1 = HID_DIM * IN_DIM / 4;      // 4096
    const int G2 = 48 * 128 / 4;              // 1536
    const int REAL2 = OUT_DIM * 128 / 4;      // 1280
    const float* s; u16* d; int j; int real;
    if (i < G1)               { s = w1l; d = w1lb; j = i;            real = G1; }
    else if (i < 2*G1)        { s = w1r; d = w1rb; j = i - G1;       real = G1; }
    else if (i < 2*G1+G2)     { s = w2l; d = w2lb; j = i - 2*G1;     real = REAL2; }
    else if (i < 2*G1+2*G2)   { s = w2r; d = w2rb; j = i - 2*G1-G2;  real = REAL2; }
    else return;
    u32x2 o;
    if (j < real) {
        float4v v = reinterpret_cast<const float4v*>(s)[j];
        o.x = ((u32)f2bf(v.y) << 16) | (u32)f2bf(v.x);
        o.y = ((u32)f2bf(v.w) << 16) | (u32)f2bf(v.z);
    } else { o.x = 0; o.y = 0; }
    reinterpret_cast<u32x2*>(d)[j] = o;
}

// ---- CSR build: radix partition by dst bucket -------------------------------

__global__ __launch_bounds__(256) void k_bcount(const int* __restrict__ idx,
                                                int* __restrict__ bucket_size) {
    __shared__ int cnt[NBUCK];
    int t = threadIdx.x;
    for (int i = t; i < NBUCK; i += 256) cnt[i] = 0;
    __syncthreads();
    int base = blockIdx.x * CHUNK;
    int n = min(CHUNK, N_EDGES - base);
    for (int i = t; i < n; i += 256)
        atomicAdd(&cnt[idx[N_EDGES + base + i] >> BSHIFT], 1);
    __syncthreads();
    for (int i = t; i < NBUCK; i += 256)
        if (cnt[i]) atomicAdd(&bucket_size[i], cnt[i]);
}

__global__ __launch_bounds__(256) void k_bscan(const int* __restrict__ bucket_size,
                                               int* __restrict__ bucket_base,
                                               int* __restrict__ bucket_cur) {
    __shared__ int sa[256], sb[256];
    int t = threadIdx.x;
    int v = (t < NBUCK) ? bucket_size[t] : 0;
    sa[t] = v;
    __syncthreads();
    int *s = sa, *d = sb;
    for (int dd = 1; dd < 256; dd <<= 1) {
        d[t] = s[t] + ((t >= dd) ? s[t - dd] : 0);
        __syncthreads();
        int* tm = s; s = d; d = tm;
    }
    if (t < NBUCK) {
        int base = s[t] - v;   // exclusive prefix
        bucket_base[t] = base;
        bucket_cur[t] = base;
    }
}

__global__ __launch_bounds__(256) void k_bscatter(const int* __restrict__ idx,
                                                  int* __restrict__ bucket_cur,
                                                  u64* __restrict__ rec) {
    __shared__ int cnt[NBUCK], lofs[NBUCK], gbase[NBUCK], cnt2[NBUCK];
    __shared__ int sa[256], sb[256];
    __shared__ u64 lrec[CHUNK];
    int t = threadIdx.x;
    for (int i = t; i < NBUCK; i += 256) { cnt[i] = 0; cnt2[i] = 0; }
    __syncthreads();
    int base = blockIdx.x * CHUNK;
    int n = min(CHUNK, N_EDGES - base);
    for (int i = t; i < n; i += 256)
        atomicAdd(&cnt[idx[N_EDGES + base + i] >> BSHIFT], 1);
    __syncthreads();
    int v = (t < NBUCK) ? cnt[t] : 0;
    sa[t] = v;
    __syncthreads();
    int *s = sa, *d = sb;
    for (int dd = 1; dd < 256; dd <<= 1) {
        d[t] = s[t] + ((t >= dd) ? s[t - dd] : 0);
        __syncthreads();
        int* tm = s; s = d; d = tm;
    }
    if (t < NBUCK) {
        lofs[t] = s[t] - v;
        gbase[t] = v ? atomicAdd(&bucket_cur[t], v) : 0;
    }
    __syncthreads();
    for (int i = t; i < n; i += 256) {
        int srcv = idx[base + i];
        int dstv = idx[N_EDGES + base + i];
        int b = dstv >> BSHIFT;
        int p = lofs[b] + atomicAdd(&cnt2[b], 1);
        lrec[p] = ((u64)(u32)dstv << 32) | (u32)srcv;
    }
    __syncthreads();
    for (int i = t; i < n; i += 256) {
        u64 r = lrec[i];
        int b = ((int)(r >> 32)) >> BSHIFT;
        rec[gbase[b] + (i - lofs[b])] = r;
    }
}

__global__ __launch_bounds__(256) void k_bfill(const u64* __restrict__ rec,
                                               const int* __restrict__ bucket_base,
                                               const int* __restrict__ bucket_size,
                                               int* __restrict__ row_start,
                                               int* __restrict__ row_end,
                                               float* __restrict__ deg_inv,
                                               int* __restrict__ csr) {
    __shared__ int deg[512], cur[512];
    __shared__ int sa[512], sb[512];
    int t = threadIdx.x;
    int b = blockIdx.x;
    int node0 = b << BSHIFT;
    int nn = min(512, N_NODES - node0);
    int ebase = bucket_base[b];
    int esz = bucket_size[b];
    for (int i = t; i < 512; i += 256) deg[i] = 0;
    __syncthreads();
    for (int i = t; i < esz; i += 256)
        atomicAdd(&deg[((int)(rec[ebase + i] >> 32)) & 511], 1);
    __syncthreads();
    for (int i = t; i < 512; i += 256) sa[i] = deg[i];
    __syncthreads();
    int *s = sa, *d = sb;
    for (int dd = 1; dd < 512; dd <<= 1) {
        for (int i = t; i < 512; i += 256) d[i] = s[i] + ((i >= dd) ? s[i - dd] : 0);
        __syncthreads();
        int* tm = s; s = d; d = tm;
    }
    for (int i = t; i < 512; i += 256) {
        int excl = s[i] - deg[i];
        cur[i] = excl;
        if (i < nn) {
            row_start[node0 + i] = ebase + excl;
            row_end[node0 + i]   = ebase + s[i];
            deg_inv[node0 + i]   = 1.0f / (float)max(deg[i], 1);
        }
    }
    __syncthreads();
    for (int i = t; i < esz; i += 256) {
        u64 r = rec[ebase + i];
        int dl = ((int)(r >> 32)) & 511;
        int p = atomicAdd(&cur[dl], 1);
        csr[ebase + p] = (int)(r & 0xffffffffu);
    }
}

// ---- Mean aggregation: one wave per dst node --------------------------------
// Edge-paired gathers: lanes split 32/32, each lane loads 8 B, so one
// instruction fetches 512 B spanning TWO source rows (2x MLP, half the load
// instructions). Index loads software-pipelined ahead of gather consumption.

__global__ void k_agg(const u16* __restrict__ feat,
                      const int* __restrict__ csr,
                      const int* __restrict__ row_start,
                      const int* __restrict__ row_end,
                      const float* __restrict__ deg_inv,
                      u16* __restrict__ agg) {
    int n = blockIdx.x * 4 + (threadIdx.x >> 6);
    int lane = threadIdx.x & 63;
    if (n >= N_NODES) return;
    int s = row_start[n];
    int e = row_end[n];
    int half = lane >> 5;     // edge of the pair
    int li = lane & 31;       // 8B chunk within row (dims 4li..4li+3)
    const u32x2* fp = reinterpret_cast<const u32x2*>(feat);   // 32 granules/row
    float a0 = 0.f, a1 = 0.f, a2 = 0.f, a3 = 0.f;
    int p = s;
    int i0 = 0, i1 = 0, i2 = 0, i3 = 0;
    if (p + 8 <= e) {
        i0 = csr[p + half];     i1 = csr[p + 2 + half];
        i2 = csr[p + 4 + half]; i3 = csr[p + 6 + half];
    }
    while (p + 8 <= e) {
        u32x2 v0 = fp[i0 * 32 + li];
        u32x2 v1 = fp[i1 * 32 + li];
        u32x2 v2 = fp[i2 * 32 + li];
        u32x2 v3 = fp[i3 * 32 + li];
        p += 8;
        if (p + 8 <= e) {       // prefetch next indices during gather latency
            i0 = csr[p + half];     i1 = csr[p + 2 + half];
            i2 = csr[p + 4 + half]; i3 = csr[p + 6 + half];
        }
        a0 += bflo(v0.x) + bflo(v1.x) + bflo(v2.x) + bflo(v3.x);
        a1 += bfhi(v0.x) + bfhi(v1.x) + bfhi(v2.x) + bfhi(v3.x);
        a2 += bflo(v0.y) + bflo(v1.y) + bflo(v2.y) + bflo(v3.y);
        a3 += bfhi(v0.y) + bfhi(v1.y) + bfhi(v2.y) + bfhi(v3.y);
    }
    for (; p + 2 <= e; p += 2) {
        int i = csr[p + half];
        u32x2 v = fp[i * 32 + li];
        a0 += bflo(v.x); a1 += bfhi(v.x);
        a2 += bflo(v.y); a3 += bfhi(v.y);
    }
    if (p < e && half == 0) {   // single leftover edge: lo-half lanes only
        int i = csr[p];
        u32x2 v = fp[i * 32 + li];
        a0 += bflo(v.x); a1 += bfhi(v.x);
        a2 += bflo(v.y); a3 += bfhi(v.y);
    }
    // fold the two halves
    a0 += __shfl_xor(a0, 32);
    a1 += __shfl_xor(a1, 32);
    a2 += __shfl_xor(a2, 32);
    a3 += __shfl_xor(a3, 32);
    if (half == 0) {
        float sc = deg_inv[n];
        u32x2 o;
        o.x = ((u32)f2bf(a1 * sc) << 16) | (u32)f2bf(a0 * sc);
        o.y = ((u32)f2bf(a3 * sc) << 16) | (u32)f2bf(a2 * sc);
        reinterpret_cast<u32x2*>(agg)[n * 32 + li] = o;
    }
}

// ---- Dense layer 1: h = relu(normalize(agg@W1l^T + b1 + x@W1r^T)) ----------
// MFMA 16x16x32 bf16. One wave = 16 nodes x 128 outs, K=256 (agg half, x half).
// D: col(o)=lane&15, row(node)=quad*4+reg.

__global__ __launch_bounds__(256) void k_dense1(
    const u16* __restrict__ agg, const u16* __restrict__ x,
    const u16* __restrict__ W1l, const u16* __restrict__ W1r,
    const float* __restrict__ b1, u16* __restrict__ h) {
    int wave = threadIdx.x >> 6;
    int lane = threadIdx.x & 63;
    int nb = blockIdx.x * 64 + wave * 16;
    int q = lane >> 4;
    int m = lane & 15;
    int arow = nb + m;
    if (arow >= N_NODES) arow = N_NODES - 1;   // clamp loads; stores are guarded

    float4v acc[8];
    #pragma unroll
    for (int ct = 0; ct < 8; ++ct) acc[ct] = (float4v){0.f, 0.f, 0.f, 0.f};

    const u16* Ap[2] = { agg, x };
    const u16* Bp[2] = { W1l, W1r };
    #pragma unroll
    for (int half = 0; half < 2; ++half) {
        const u16* A = Ap[half];
        const u16* B = Bp[half];
        #pragma unroll
        for (int ks = 0; ks < 4; ++ks) {
            int k0 = ks * 32 + q * 8;
            short8 a = *reinterpret_cast<const short8*>(A + arow * 128 + k0);
            #pragma unroll
            for (int ct = 0; ct < 8; ++ct) {
                short8 b = *reinterpret_cast<const short8*>(B + (ct * 16 + m) * 128 + k0);
                acc[ct] = __builtin_amdgcn_mfma_f32_16x16x32_bf16(a, b, acc[ct], 0, 0, 0);
            }
        }
    }

    float bias[8];
    #pragma unroll
    for (int ct = 0; ct < 8; ++ct) bias[ct] = b1[ct * 16 + m];

    float nsq[4] = { 0.f, 0.f, 0.f, 0.f };
    #pragma unroll
    for (int ct = 0; ct < 8; ++ct)
        #pragma unroll
        for (int r = 0; r < 4; ++r) {
            float v = acc[ct][r] + bias[ct];
            acc[ct][r] = v;
            nsq[r] += v * v;
        }
    #pragma unroll
    for (int r = 0; r < 4; ++r) {
        float t = nsq[r];
        t += __shfl_xor(t, 1);
        t += __shfl_xor(t, 2);
        t += __shfl_xor(t, 4);
        t += __shfl_xor(t, 8);
        nsq[r] = 1.0f / fmaxf(sqrtf(t), 1e-12f);
    }
    #pragma unroll
    for (int r = 0; r < 4; ++r) {
        int node = nb + q * 4 + r;
        if (node < N_NODES) {
            #pragma unroll
            for (int ct = 0; ct < 8; ++ct) {
                float v = fmaxf(acc[ct][r] * nsq[r], 0.0f);
                h[node * 128 + ct * 16 + m] = f2bf(v);
            }
        }
    }
}

// ---- Dense layer 2 + log_softmax, MFMA version ------------------------------
// One wave = 16 nodes x 48 cols (3 ct tiles; cols 40..47 zero-padded weights).

__global__ __launch_bounds__(256) void k_dense2(
    const u16* __restrict__ agg, const u16* __restrict__ hfeat,
    const u16* __restrict__ W2lb, const u16* __restrict__ W2rb,
    const float* __restrict__ b2, float* __restrict__ out) {
    int wave = threadIdx.x >> 6;
    int lane = threadIdx.x & 63;
    int nb = blockIdx.x * 64 + wave * 16;
    int q = lane >> 4;
    int m = lane & 15;
    int arow = nb + m;
    if (arow >= N_NODES) arow = N_NODES - 1;

    float4v acc[3];
    #pragma unroll
    for (int ct = 0; ct < 3; ++ct) acc[ct] = (float4v){0.f, 0.f, 0.f, 0.f};

    const u16* Ap[2] = { agg, hfeat };
    const u16* Bp[2] = { W2lb, W2rb };
    #pragma unroll
    for (int half = 0; half < 2; ++half) {
        const u16* A = Ap[half];
        const u16* B = Bp[half];
        #pragma unroll
        for (int ks = 0; ks < 4; ++ks) {
            int k0 = ks * 32 + q * 8;
            short8 a = *reinterpret_cast<const short8*>(A + arow * 128 + k0);
            #pragma unroll
            for (int ct = 0; ct < 3; ++ct) {
                short8 b = *reinterpret_cast<const short8*>(B + (ct * 16 + m) * 128 + k0);
                acc[ct] = __builtin_amdgcn_mfma_f32_16x16x32_bf16(a, b, acc[ct], 0, 0, 0);
            }
        }
    }

    float bias[3];
    #pragma unroll
    for (int ct = 0; ct < 3; ++ct) {
        int row = ct * 16 + m;
        bias[ct] = (row < OUT_DIM) ? b2[row] : 0.0f;
    }

    float nsq[4] = { 0.f, 0.f, 0.f, 0.f };
    #pragma unroll
    for (int ct = 0; ct < 3; ++ct)
        #pragma unroll
        for (int r = 0; r < 4; ++r) {
            float v = acc[ct][r] + bias[ct];
            acc[ct][r] = v;
            nsq[r] += v * v;
        }
    #pragma unroll
    for (int r = 0; r < 4; ++r) {
        float t = nsq[r];
        t += __shfl_xor(t, 1);
        t += __shfl_xor(t, 2);
        t += __shfl_xor(t, 4);
        t += __shfl_xor(t, 8);
        nsq[r] = 1.0f / fmaxf(sqrtf(t), 1e-12f);
    }

    float mv[4] = { 0.f, 0.f, 0.f, 0.f };
    #pragma unroll
    for (int ct = 0; ct < 3; ++ct)
        #pragma unroll
        for (int r = 0; r < 4; ++r) {
            float v = fmaxf(acc[ct][r] * nsq[r], 0.0f);
            acc[ct][r] = v;
            mv[r] = fmaxf(mv[r], v);
        }
    #pragma unroll
    for (int r = 0; r < 4; ++r) {
        float t = mv[r];
        t = fmaxf(t, __shfl_xor(t, 1));
        t = fmaxf(t, __shfl_xor(t, 2));
        t = fmaxf(t, __shfl_xor(t, 4));
        t = fmaxf(t, __shfl_xor(t, 8));
        mv[r] = t;
    }

    float se[4] = { 0.f, 0.f, 0.f, 0.f };
    #pragma unroll
    for (int ct = 0; ct < 3; ++ct) {
        bool valid = (ct < 2) || (m < 8);
        #pragma unroll
        for (int r = 0; r < 4; ++r)
            se[r] += valid ? __expf(acc[ct][r] - mv[r]) : 0.0f;
    }
    #pragma unroll
    for (int r = 0; r < 4; ++r) {
        float t = se[r];
        t += __shfl_xor(t, 1);
        t += __shfl_xor(t, 2);
        t += __shfl_xor(t, 4);
        t += __shfl_xor(t, 8);
        se[r] = __logf(t);
    }

    #pragma unroll
    for (int r = 0; r < 4; ++r) {
        int node = nb + q * 4 + r;
        if (node < N_NODES) {
            #pragma unroll
            for (int ct = 0; ct < 3; ++ct) {
                int col = ct * 16 + m;
                if (col < OUT_DIM)
                    out[node * OUT_DIM + col] = acc[ct][r] - mv[r] - se[r];
            }
        }
    }
}

// ---- launch -----------------------------------------------------------------

extern "C" void kernel_launch(void* const* d_in, const int* in_sizes, int n_in,
                              void* d_out, int out_size, void* d_ws, size_t ws_size,
                              hipStream_t stream) {
    const float* x   = (const float*)d_in[0];
    const int*   idx = (const int*)d_in[1];
    const float* W1l = (const float*)d_in[2];
    const float* b1  = (const float*)d_in[3];
    const float* W1r = (const float*)d_in[4];
    const float* W2l = (const float*)d_in[5];
    const float* b2  = (const float*)d_in[6];
    const float* W2r = (const float*)d_in[7];
    float* out = (float*)d_out;

    char* ws = (char*)d_ws;
    int*   bucket_size = (int*)(ws + 0);        // 784 B (memset 0)
    int*   bucket_base = (int*)(ws + 4096);     // 784 B
    int*   bucket_cur  = (int*)(ws + 8192);     // 784 B
    int*   row_start   = (int*)(ws + 16384);    // 400000 B
    int*   row_end     = (int*)(ws + 416384);   // 400000 B
    float* deg_inv     = (float*)(ws + 816384); // 400000 B
    int*   csr         = (int*)(ws + 1216384);  // 6.4 MB -> ends 7616384
    u16*   xb          = (u16*)(ws + 7616512);  // 25.6 MB bf16(x)
    u16*   agg         = (u16*)(ws + 33216512); // 25.6 MB
    u16*   h           = (u16*)(ws + 58816512); // 25.6 MB
    u64*   rec         = (u64*)(ws + 58816512); // 12.8 MB, ALIASES h (disjoint lifetime)
    u16*   W1lb        = (u16*)(ws + 84416512); // 32768 B
    u16*   W1rb        = (u16*)(ws + 84449280); // 32768 B
    u16*   W2lb        = (u16*)(ws + 84482048); // 12288 B (48x128 padded)
    u16*   W2rb        = (u16*)(ws + 84494336); // 12288 B

    hipMemsetAsync(bucket_size, 0, NBUCK * sizeof(int), stream);

    // bf16 conversions
    k_cvt<<<(N_NODES * IN_DIM / 4 + 255) / 256, 256, 0, stream>>>(x, xb, N_NODES * IN_DIM / 4);
    k_cvtw<<<44, 256, 0, stream>>>(W1l, W1r, W2l, W2r, W1lb, W1rb, W2lb, W2rb);

    // CSR build via radix partition
    k_bcount<<<NCHUNK, 256, 0, stream>>>(idx, bucket_size);
    k_bscan<<<1, 256, 0, stream>>>(bucket_size, bucket_base, bucket_cur);
    k_bscatter<<<NCHUNK, 256, 0, stream>>>(idx, bucket_cur, rec);
    k_bfill<<<NBUCK, 256, 0, stream>>>(rec, bucket_base, bucket_size,
                                       row_start, row_end, deg_inv, csr);

    // layer 1
    k_agg<<<N_NODES / 4, 256, 0, stream>>>(xb, csr, row_start, row_end, deg_inv, agg);
    k_dense1<<<(N_NODES + 63) / 64, 256, 0, stream>>>(agg, xb, W1lb, W1rb, b1, h);
    // layer 2
    k_agg<<<N_NODES / 4, 256, 0, stream>>>(h, csr, row_start, row_end, deg_inv, agg);
    k_dense2<<<(N_NODES + 63) / 64, 256, 0, stream>>>(agg, h, W2lb, W2rb, b2, out);
}